// Round 10
// baseline (41.909 us; speedup 1.0000x reference)
//
#include <hip/hip_runtime.h>

#define NB 16
#define NT 50
#define NA 5
#define NH 152
#define NW 152
#define CH 70             // NA*(7+NC)
#define HW (NH*NW)        // 23104
#define AHW (NA*HW)       // 115520
#define NCELL (NB*AHW)    // 1,848,320
#define NTGT (NB*NT)      // 800

#define NSUMB 452
#define SUM_IT 4          // 452*256*4*4 >= NCELL (bounds-checked)
#define GRID_MAIN (NTGT + 1 + NSUMB)    // 1253
#define CAP 2944          // >= max rect 24*24*5 + NA

// ws float layout (SoA descriptors + private per-block slots, no global atomics)
#define P_GX   0
#define P_GY   800
#define P_GW   1600
#define P_GL   2400
#define P_XLO  3200
#define P_XHI  4000
#define P_YLO  4800
#define P_YHI  5600
#define P_Q    6400
#define P_TW   7200
#define P_TL   8000
#define P_TIM  8800
#define P_TRE  9600
#define P_META 10400      // 800 ints + [800] = wrap flag
#define S_SUM  11264      // 452: softplus grand-total partials
#define S_SUB  11716      // 801: excluded-cell softplus sums
#define S_CNT  12517      // 801: excluded-cell counts
#define S_WIN  13318      // 801 x 8: winner loss terms

// meta bits: gi[0:8) gj[8:16) bn[16:19) am[19:24) valid[24] validp[25] dup[26] lab[27:30)

__device__ __forceinline__ float sp_f(float v) {
    return (v > 20.f) ? v : __logf(1.f + __expf(v));
}

struct Box { float xlo, xhi, ylo, yhi, w, h, qb; };

// contract(off): bit-identical at every inline site (ownership dedup needs
// cross-site agreement; FMA contraction is the only hazard).
__device__ __forceinline__ Box build_box(const float* __restrict__ xp,
                                         float aw, float ah, int i, int j) {
    #pragma clang fp contract(off)
    float l0 = xp[0], l1 = xp[HW], l2 = xp[2 * HW], l3 = xp[3 * HW];
    float sx = 1.f / (1.f + __expf(-l0));
    float sy = 1.f / (1.f + __expf(-l1));
    float bxv = (float)i + sx;
    float byv = (float)j + sy;
    float bw = __expf(l2) * aw, bh = __expf(l3) * ah;
    float hw2 = 0.5f * bw, hh2 = 0.5f * bh;
    Box o;
    o.xlo = bxv - hw2; o.xhi = bxv + hw2;
    o.ylo = byv - hh2; o.yhi = byv + hh2;
    o.w = bw; o.h = bh; o.qb = 0.375f * bw * bh;
    return o;
}

__device__ __forceinline__ bool excl_eval(const Box& bb, int i, int j, int a,
                                          int valid, int validp,
                                          int gi, int gj, int bn, int am,
                                          float xlo, float xhi, float ylo, float yhi,
                                          float gw, float gl, float q) {
    #pragma clang fp contract(off)
    if (valid && i == gi && j == gj && (a == bn || ((am >> a) & 1))) return true;
    if (validp) {
        float mx = fminf(bb.xlo, xlo), Mx = fmaxf(bb.xhi, xhi);
        float my = fminf(bb.ylo, ylo), My = fmaxf(bb.yhi, yhi);
        float cw = bb.w + gw - (Mx - mx);
        float ch = bb.h + gl - (My - my);
        // iou > 0.6  <=>  carea > 0.375*(area_b + area_g)
        if (cw > 0.f && ch > 0.f && cw * ch > bb.qb + q) return true;
    }
    return false;
}

// o[0..6]=loss terms, o[7]=count; lab via select (no scratch)
__device__ __forceinline__ void win_terms(const float* __restrict__ xp,
                                          float tx, float ty, float twv, float tlv,
                                          float timv, float trev, int lab,
                                          float* __restrict__ o) {
    float l[14];
    #pragma unroll
    for (int c = 0; c < 14; ++c) l[c] = xp[c * HW];
    float px = 1.f / (1.f + __expf(-l[0]));
    float py = 1.f / (1.f + __expf(-l[1]));
    o[0] = (px - tx) * (px - tx);
    o[1] = (py - ty) * (py - ty);
    float dw = l[2] - twv; o[2] = dw * dw;
    float dh = l[3] - tlv; o[3] = dh * dh;
    float di = l[4] - timv, dr = l[5] - trev;
    o[4] = di * di + dr * dr;
    o[5] = sp_f(-l[6]);
    float mx = l[7];
    #pragma unroll
    for (int c = 8; c < 14; ++c) mx = fmaxf(mx, l[c]);
    float e[7], se = 0.f;
    #pragma unroll
    for (int c = 0; c < 7; ++c) { e[c] = __expf(l[7 + c] - mx); se += e[c]; }
    float se2 = 0.f, slab = 0.f;
    #pragma unroll
    for (int c = 0; c < 7; ++c) {
        float s = e[c] / se;
        se2 += __expf(s);
        if (c == lab) slab = s;
    }
    o[6] = __logf(se2) - slab;
    o[7] = 1.f;
}

// ---------------- K_prep: one block per batch, descriptors once ------------
__global__ void __launch_bounds__(256) k_prep(const float* __restrict__ tgt,
                                              const float* __restrict__ anc,
                                              float* __restrict__ ws) {
    __shared__ int s_nz[NT], s_valid[NT], s_gi[NT], s_gj[NT], s_bn[NT];
    __shared__ int s_wrap;
    int tid = threadIdx.x, b = blockIdx.x;
    if (tid == 0) s_wrap = 0;

    float gx = 0.f, gy = 0.f, gw = 0.f, gl = 0.f, ti = 0.f, tr = 0.f;
    float twv = 0.f, tlv = 0.f;
    int bn = 0, am = 0, lab = 0;
    if (tid < NT) {
        const float* tp = tgt + (size_t)(b * NT + tid) * 7;
        float l7 = tp[0], cx = tp[1], cy = tp[2], w7 = tp[3], h7 = tp[4];
        ti = tp[5]; tr = tp[6];
        s_nz[tid] = (cx != 0.f) ? 1 : 0;
        s_valid[tid] = ((l7 + cx + cy + w7 + h7 + ti + tr) != 0.f) ? 1 : 0;
        gx = cx * NW; gy = cy * NH; gw = w7 * NW; gl = h7 * NH;
        s_gi[tid] = min(max((int)gx, 0), NW - 1);
        s_gj[tid] = min(max((int)gy, 0), NH - 1);
        float agt = (gw + 1.f) * (gl + 1.f);
        float best = -1.f;
        float awb = 1.f, ahb = 1.f;
        for (int a = 0; a < NA; ++a) {
            float aw = anc[2 * a], ah = anc[2 * a + 1];
            float iw = fmaxf(fminf(gw, aw) + 1.f, 0.f);
            float ih = fmaxf(fminf(gl, ah) + 1.f, 0.f);
            float inter = iw * ih;
            float aan = (aw + 1.f) * (ah + 1.f);
            float iou = inter / (agt + aan - inter + 1e-16f);
            if (iou > best) { best = iou; bn = a; awb = aw; ahb = ah; }
            if (iou > 0.6f) am |= (1 << a);
        }
        s_bn[tid] = bn;
        twv = logf(gw / awb + 1e-16f);
        tlv = logf(gl / ahb + 1e-16f);
        lab = ((int)l7) & 7;
    }
    // block 0: global wrap flag (any all-zero target row anywhere)
    if (b == 0) {
        for (int id = tid; id < NTGT; id += 256) {
            const float* tp = tgt + (size_t)id * 7;
            float s7 = tp[0] + tp[1] + tp[2] + tp[3] + tp[4] + tp[5] + tp[6];
            if (s7 == 0.f) s_wrap = 1;   // benign monotone race
        }
    }
    __syncthreads();

    if (tid < NT) {
        int id = b * NT + tid;
        int vp = 1;
        for (int u = 0; u <= tid; ++u) vp &= s_nz[u];
        int dup = 0;
        if (s_valid[tid]) {
            for (int t2 = tid + 1; t2 < NT; ++t2) {
                if (s_valid[t2] && s_gi[t2] == s_gi[tid] &&
                    s_gj[t2] == s_gj[tid] && s_bn[t2] == s_bn[tid]) { dup = 1; break; }
            }
        }
        ws[P_GX + id]  = gx;  ws[P_GY + id]  = gy;
        ws[P_GW + id]  = gw;  ws[P_GL + id]  = gl;
        ws[P_XLO + id] = gx - 0.5f * gw; ws[P_XHI + id] = gx + 0.5f * gw;
        ws[P_YLO + id] = gy - 0.5f * gl; ws[P_YHI + id] = gy + 0.5f * gl;
        ws[P_Q + id]   = 0.375f * gw * gl;
        ws[P_TW + id]  = twv; ws[P_TL + id] = tlv;
        ws[P_TIM + id] = ti;  ws[P_TRE + id] = tr;
        ((int*)ws)[P_META + id] =
            s_gi[tid] | (s_gj[tid] << 8) | (s_bn[tid] << 16) | (am << 19)
            | (s_valid[tid] << 24) | (vp << 25) | (dup << 26) | (lab << 27);
    }
    if (b == 0 && tid == 0) ((int*)ws)[P_META + NTGT] = s_wrap;
}

// ---------------- K_main: rect+winner / c* / sum roles ---------------------
__global__ void __launch_bounds__(256) k_main(const float* __restrict__ x,
                                              const float* __restrict__ anc,
                                              float* __restrict__ ws) {
    __shared__ float redA[256], redB[256];
    int tid = threadIdx.x, bx = blockIdx.x;

    // ---- role: unmasked grand softplus(l6) sum (trailing blocks) ----
    if (bx > NTGT) {
        int sx = bx - NTGT - 1;
        float s = 0.f;
        for (int it = 0; it < SUM_IT; ++it) {
            int c4 = (((it * NSUMB + sx) * 256) + tid) * 4;
            if (c4 < NCELL) {
                int b = c4 / AHW;
                int within = c4 - b * AHW;
                int a = within / HW;
                int rem = within - a * HW;
                const float* p = x + (size_t)(b * CH + a * 14 + 6) * HW + rem;
                float4 v = *(const float4*)p;
                s += sp_f(v.x) + sp_f(v.y) + sp_f(v.z) + sp_f(v.w);
            }
        }
        redA[tid] = s;
        __syncthreads();
        for (int st = 128; st > 0; st >>= 1) {
            if (tid < st) redA[tid] += redA[tid + st];
            __syncthreads();
        }
        if (tid == 0) ws[S_SUM + sx] = redA[0];
        return;
    }

    // ---- rect / c* roles: load batch descriptors from ws (computed once) --
    __shared__ float s_gx[NT], s_gy[NT], s_gw[NT], s_gl[NT];
    __shared__ float s_xlo[NT], s_xhi[NT], s_ylo[NT], s_yhi[NT], s_q[NT];
    __shared__ int s_meta[NT];
    __shared__ float s_aw[NA], s_ah[NA];
    __shared__ int s_stack[CAP];
    __shared__ int s_n;

    bool isC = (bx == NTGT);
    int tt = isC ? (NTGT - 1) : bx;          // c* uses batch 15
    int b = tt / NT;
    int t = isC ? NT : (tt - b * NT);

    if (tid < NA) { s_aw[tid] = anc[2 * tid]; s_ah[tid] = anc[2 * tid + 1]; }
    if (tid == 0) s_n = 0;
    if (tid < NT) {
        int id = b * NT + tid;
        s_gx[tid] = ws[P_GX + id];  s_gy[tid] = ws[P_GY + id];
        s_gw[tid] = ws[P_GW + id];  s_gl[tid] = ws[P_GL + id];
        s_xlo[tid] = ws[P_XLO + id]; s_xhi[tid] = ws[P_XHI + id];
        s_ylo[tid] = ws[P_YLO + id]; s_yhi[tid] = ws[P_YHI + id];
        s_q[tid] = ws[P_Q + id];
        s_meta[tid] = ((const int*)ws)[P_META + id];
    }
    __syncthreads();

    auto excl_u = [&](const Box& bb, int i, int j, int a, int u) -> bool {
        int m = s_meta[u];
        return excl_eval(bb, i, j, a, (m >> 24) & 1, (m >> 25) & 1,
                         m & 255, (m >> 8) & 255, (m >> 16) & 7, (m >> 19) & 31,
                         s_xlo[u], s_xhi[u], s_ylo[u], s_yhi[u],
                         s_gw[u], s_gl[u], s_q[u]);
    };

    if (isC) {
        // ---- c* block: np negative-index wrap cell ----
        if (tid == 0) {
            int wrap = ((const int*)ws)[P_META + NTGT];
            float slot[8] = {0.f, 0.f, 0.f, 0.f, 0.f, 0.f, 0.f, 0.f};
            float sub = 0.f, cnt = 0.f;
            if (wrap) {
                const float* xp = x + (size_t)((NB - 1) * CH + (NA - 1) * 14) * HW
                                  + (HW - 1);
                float L16 = logf(1e-16f);
                win_terms(xp, 0.f, 0.f, L16, L16, 0.f, 0.f, 0, slot);
                int i = NW - 1, j = NH - 1, a = NA - 1;
                Box bb = build_box(xp, s_aw[a], s_ah[a], i, j);
                bool any = false;
                for (int u = 0; u < NT; ++u)
                    if (excl_u(bb, i, j, a, u)) { any = true; break; }
                if (!any) { sub = sp_f(xp[6 * HW]); cnt = 1.f; }
            }
            float* dst = ws + S_WIN + NTGT * 8;
            #pragma unroll
            for (int k = 0; k < 8; ++k) dst[k] = slot[k];
            ws[S_SUB + NTGT] = sub;
            ws[S_CNT + NTGT] = cnt;
        }
        return;
    }

    int mt = s_meta[t];
    int valid = (mt >> 24) & 1, validp = (mt >> 25) & 1, dup = (mt >> 26) & 1;
    int gi = mt & 255, gj = (mt >> 8) & 255, bn = (mt >> 16) & 7;
    int am = (mt >> 19) & 31, lab = (mt >> 27) & 7;

    // ---- winner slot (tid 0) ----
    if (tid == 0) {
        float slot[8] = {0.f, 0.f, 0.f, 0.f, 0.f, 0.f, 0.f, 0.f};
        if (valid && !dup) {   // last-t-wins (np scatter order)
            int id = tt;
            const float* xp = x + (size_t)(b * CH + bn * 14) * HW + gj * NW + gi;
            win_terms(xp, s_gx[t] - (float)gi, s_gy[t] - (float)gj,
                      ws[P_TW + id], ws[P_TL + id],
                      ws[P_TIM + id], ws[P_TRE + id], lab, slot);
        }
        float* dst = ws + S_WIN + tt * 8;
        #pragma unroll
        for (int k = 0; k < 8; ++k) dst[k] = slot[k];
    }

    // ---- phase 1: E_t only (1 eval/cell), hits -> LDS stack ----
    bool vp = validp && s_gw[t] > 0.f && s_gl[t] > 0.f;
    int i_lo = 0, j_lo = 0, W = 0, Hh = 0, rectTotal = 0;
    if (vp) {
        // proven reach: IoU pass => |bx-gx| < gw/3, |by-gy| < gl/3 (+1 margin)
        float gw3 = s_gw[t] * (1.f / 3.f), gl3 = s_gl[t] * (1.f / 3.f);
        i_lo = max(0, (int)floorf(s_gx[t] - gw3) - 1);
        int i_hi = min(NW - 1, (int)floorf(s_gx[t] + gw3) + 1);
        j_lo = max(0, (int)floorf(s_gy[t] - gl3) - 1);
        int j_hi = min(NH - 1, (int)floorf(s_gy[t] + gl3) + 1);
        W = i_hi - i_lo + 1; Hh = j_hi - j_lo + 1;
        rectTotal = W * Hh * NA;
    }
    int extra = (valid && !vp) ? NA : 0;     // safety: override cells off-rect
    int total = rectTotal + extra;
    for (int idx = tid; idx < total; idx += 256) {
        int i, j, a;
        if (idx < rectTotal) {
            int dx = idx % W;
            int q2 = idx / W;
            j = j_lo + q2 % Hh;
            a = q2 / Hh;
            i = i_lo + dx;
        } else {
            a = idx - rectTotal; i = gi; j = gj;
            if (!(a == bn || ((am >> a) & 1))) continue;
        }
        const float* xp = x + (size_t)(b * CH + a * 14) * HW + j * NW + i;
        Box bb = build_box(xp, s_aw[a], s_ah[a], i, j);
        if (excl_u(bb, i, j, a, t)) {
            int pos = atomicAdd(&s_n, 1);
            if (pos < CAP) s_stack[pos] = (a << 16) | (j << 8) | i;
        }
    }
    __syncthreads();

    // ---- phase 2: compacted dedup scan (owner iff no u<t excludes) ----
    int n = min(s_n, CAP);
    float sub_s = 0.f, cnt_s = 0.f;
    for (int k = tid; k < n; k += 256) {
        int pk = s_stack[k];
        int i = pk & 255, j = (pk >> 8) & 255, a = pk >> 16;
        const float* xp = x + (size_t)(b * CH + a * 14) * HW + j * NW + i;
        Box bb = build_box(xp, s_aw[a], s_ah[a], i, j);
        bool owned = true;
        for (int u = 0; u < t; ++u)
            if (excl_u(bb, i, j, a, u)) { owned = false; break; }
        if (owned) {
            sub_s += sp_f(xp[6 * HW]);
            cnt_s += 1.f;
        }
    }
    redA[tid] = sub_s; redB[tid] = cnt_s;
    __syncthreads();
    for (int st = 128; st > 0; st >>= 1) {
        if (tid < st) { redA[tid] += redA[tid + st]; redB[tid] += redB[tid + st]; }
        __syncthreads();
    }
    if (tid == 0) { ws[S_SUB + tt] = redA[0]; ws[S_CNT + tt] = redB[0]; }
}

// ---------------- tiny deterministic reduce + loss assembly ----------------
__global__ void __launch_bounds__(256) k_reduce2(const float* __restrict__ ws,
                                                 float* __restrict__ out) {
    int tid = threadIdx.x;
    double acc[11];
    #pragma unroll
    for (int k = 0; k < 11; ++k) acc[k] = 0.0;
    for (int s = tid; s < NTGT + 1; s += 256) {
        const float* p = ws + S_WIN + s * 8;
        #pragma unroll
        for (int k = 0; k < 8; ++k) acc[k] += (double)p[k];
        acc[8] += (double)ws[S_SUB + s];
        acc[9] += (double)ws[S_CNT + s];
    }
    for (int s = tid; s < NSUMB; s += 256) acc[10] += (double)ws[S_SUM + s];

    __shared__ double R[11][256];
    #pragma unroll
    for (int k = 0; k < 11; ++k) R[k][tid] = acc[k];
    __syncthreads();
    for (int st = 128; st > 0; st >>= 1) {
        if (tid < st) {
            #pragma unroll
            for (int k = 0; k < 11; ++k) R[k][tid] += R[k][tid + st];
        }
        __syncthreads();
    }
    if (tid == 0) {
        double nM  = fmax(R[7][0], 1.0);
        double scf = fmax((double)NCELL - R[9][0], 1.0);
        double bce = R[10][0] - R[8][0];
        double loss =
            (R[0][0] + R[1][0] + R[2][0] + R[3][0] + R[4][0] + R[5][0]) / nM
            + bce / scf
            + (1.0 / NB) * R[6][0] / nM;
        out[0] = (float)loss;
    }
}

extern "C" void kernel_launch(void* const* d_in, const int* in_sizes, int n_in,
                              void* d_out, int out_size, void* d_ws, size_t ws_size,
                              hipStream_t stream) {
    const float* x   = (const float*)d_in[0];
    const float* tgt = (const float*)d_in[1];
    const float* anc = (const float*)d_in[2];
    float* ws  = (float*)d_ws;
    float* out = (float*)d_out;

    hipLaunchKernelGGL(k_prep, dim3(NB), dim3(256), 0, stream, tgt, anc, ws);
    hipLaunchKernelGGL(k_main, dim3(GRID_MAIN), dim3(256), 0, stream, x, anc, ws);
    hipLaunchKernelGGL(k_reduce2, dim3(1), dim3(256), 0, stream, ws, out);
}

// Round 11
// 29.656 us; speedup vs baseline: 1.4132x; 1.4132x over previous
//
#include <hip/hip_runtime.h>

#define NB 16
#define NT 50
#define NA 5
#define NH 152
#define NW 152
#define CH 70             // NA*(7+NC)
#define HW (NH*NW)        // 23104
#define AHW (NA*HW)       // 115520
#define NCELL (NB*AHW)    // 1,848,320
#define NWORDS (NCELL/32) // 57,760
#define NTGT (NB*NT)      // 800

#define NSUMB 452
#define SUM_IT 4          // 452*256*4*4 >= NCELL (bounds-checked)
#define GRID2 (NTGT + NTGT + 1 + NSUMB)   // 800 scatter + 801 winner + 452 sum

// ws float layout (within round-5's proven 326 KB footprint)
#define D_XLO 0
#define D_XHI 800
#define D_YLO 1600
#define D_YHI 2400
#define D_GW  3200
#define D_GL  4000
#define D_Q   4800
#define D_TW  5600
#define D_TL  6400
#define D_TIM 7200
#define D_TRE 8000
#define D_GX  8800
#define D_GY  9600
#define D_META 10400      // 800 ints
#define S_SUM 11200       // 452 grand-sum partials
#define S_SUB 11712       // 801 first-setter subtract partials
#define S_CNT 12520       // 801 first-setter counts
#define M_WORD 16384      // u32 mask bits [16384,74144)
#define S_WIN 74144       // 801 x 8 winner slots -> ends 80552 (322 KB)

// meta bits: gi[0:8) gj[8:16) bn[16:19) am[19:24) valid[24] validp[25] lab[26:29)

__device__ __forceinline__ float sp_f(float v) {
    return (v > 20.f) ? v : __logf(1.f + __expf(v));
}

__device__ __forceinline__ void prep_one(int id, const float* __restrict__ tgt,
                                         const float* __restrict__ anchors,
                                         float* __restrict__ ws) {
    int b = id / NT, t = id - b * NT;
    const float* tp = tgt + id * 7;
    float lab = tp[0], cx = tp[1], cy = tp[2], w = tp[3], l = tp[4];
    float tim = tp[5], tre = tp[6];
    float sum = lab + cx + cy + w + l + tim + tre;
    bool valid = (sum != 0.0f);
    bool validp = true;
    const float* tb = tgt + (size_t)b * NT * 7;
    for (int t2 = 0; t2 <= t; ++t2) validp = validp && (tb[t2 * 7 + 1] != 0.0f);

    float gx = cx * NW, gy = cy * NH, gw = w * NW, gl = l * NH;
    int gi = min(max((int)gx, 0), NW - 1);
    int gj = min(max((int)gy, 0), NH - 1);

    float agt = (gw + 1.f) * (gl + 1.f);
    float best = -1.f; int bn = 0, am = 0;
    float aw_b = 1.f, ah_b = 1.f;
    for (int a = 0; a < NA; ++a) {
        float aw = anchors[2 * a], ah = anchors[2 * a + 1];
        float iw = fmaxf(fminf(gw, aw) + 1.f, 0.f);
        float ih = fmaxf(fminf(gl, ah) + 1.f, 0.f);
        float inter = iw * ih;
        float aan = (aw + 1.f) * (ah + 1.f);
        float iou = inter / (agt + aan - inter + 1e-16f);
        if (iou > best) { best = iou; bn = a; aw_b = aw; ah_b = ah; }
        if (iou > 0.6f) am |= (1 << a);
    }

    ws[D_XLO + id] = gx - 0.5f * gw;
    ws[D_XHI + id] = gx + 0.5f * gw;
    ws[D_YLO + id] = gy - 0.5f * gl;
    ws[D_YHI + id] = gy + 0.5f * gl;
    ws[D_GW + id]  = gw;
    ws[D_GL + id]  = gl;
    ws[D_Q + id]   = 0.375f * gw * gl;
    ws[D_TW + id]  = logf(gw / aw_b + 1e-16f);
    ws[D_TL + id]  = logf(gl / ah_b + 1e-16f);
    ws[D_TIM + id] = tim;
    ws[D_TRE + id] = tre;
    ws[D_GX + id]  = gx;
    ws[D_GY + id]  = gy;

    int meta = 0;
    if (valid || validp) {
        meta = gi | (gj << 8) | (bn << 16) | (am << 19)
             | (valid ? (1 << 24) : 0) | (validp ? (1 << 25) : 0)
             | ((((int)lab) & 7) << 26);
    }
    ((int*)ws)[D_META + id] = meta;
}

// o[0..6]=loss terms, o[7]=count; lab via select (no scratch)
__device__ __forceinline__ void win_terms(const float* __restrict__ xp,
                                          float tx, float ty, float twv, float tlv,
                                          float timv, float trev, int lab,
                                          float* __restrict__ o) {
    float l[14];
    #pragma unroll
    for (int c = 0; c < 14; ++c) l[c] = xp[c * HW];
    float px = 1.f / (1.f + __expf(-l[0]));
    float py = 1.f / (1.f + __expf(-l[1]));
    o[0] = (px - tx) * (px - tx);
    o[1] = (py - ty) * (py - ty);
    float dw = l[2] - twv; o[2] = dw * dw;
    float dh = l[3] - tlv; o[3] = dh * dh;
    float di = l[4] - timv, dr = l[5] - trev;
    o[4] = di * di + dr * dr;
    o[5] = sp_f(-l[6]);
    float mx = l[7];
    #pragma unroll
    for (int c = 8; c < 14; ++c) mx = fmaxf(mx, l[c]);
    float e[7], se = 0.f;
    #pragma unroll
    for (int c = 0; c < 7; ++c) { e[c] = __expf(l[7 + c] - mx); se += e[c]; }
    float se2 = 0.f, slab = 0.f;
    #pragma unroll
    for (int c = 0; c < 7; ++c) {
        float s = e[c] / se;
        se2 += __expf(s);
        if (c == lab) slab = s;
    }
    o[6] = __logf(se2) - slab;
    o[7] = 1.f;
}

// ---------- K1: zero mask + prep descriptors (round-5 proven) ----------
__global__ void __launch_bounds__(256) k_prep_zero(const float* __restrict__ tgt,
                                                   const float* __restrict__ anchors,
                                                   float* __restrict__ ws) {
    int gtid = blockIdx.x * 256 + threadIdx.x;
    if (gtid < NWORDS) ((unsigned int*)ws)[M_WORD + gtid] = 0u;
    if (gtid < NTGT) prep_one(gtid, tgt, anchors, ws);
}

// ---------- K2: scatter(+first-set subtract) / winner / grand-sum ----------
__global__ void __launch_bounds__(256) k_work(const float* __restrict__ x,
                                              const float* __restrict__ tgt,
                                              const float* __restrict__ anchors,
                                              float* __restrict__ ws) {
    __shared__ float redA[256], redB[256];
    int tid = threadIdx.x, bx = blockIdx.x;
    const int* meta = (const int*)ws + D_META;
    unsigned int* mask = (unsigned int*)ws + M_WORD;

    if (bx < NTGT) {
        // ---- scatter role: iou rect + overrides; subtract on first-set ----
        int id = bx;
        int b = id / NT;
        int mt = meta[id];
        float sub = 0.f, cnt = 0.f;

        if ((mt & (1 << 24)) && tid == 0) {
            int gi = mt & 255, gj = (mt >> 8) & 255;
            int bn = (mt >> 16) & 7, am = (mt >> 19) & 31;
            for (int a = 0; a < NA; ++a) {
                if (((am >> a) & 1) || a == bn) {
                    int c = ((b * NA + a) * NH + gj) * NW + gi;
                    unsigned int old = atomicOr(&mask[c >> 5], 1u << (c & 31));
                    if (!((old >> (c & 31)) & 1u)) {
                        cnt += 1.f;
                        sub += sp_f(x[(size_t)(b * CH + a * 14 + 6) * HW + gj * NW + gi]);
                    }
                }
            }
        }
        if (mt & (1 << 25)) {
            float gxv = ws[D_GX + id], gyv = ws[D_GY + id];
            float tgw = ws[D_GW + id], tgl = ws[D_GL + id];
            float txlo = ws[D_XLO + id], txhi = ws[D_XHI + id];
            float tylo = ws[D_YLO + id], tyhi = ws[D_YHI + id];
            float tq = ws[D_Q + id];
            if (tgw > 0.f && tgl > 0.f) {
                // proven reach: pass => |bx-gx| < gw/3, |by-gy| < gl/3 (+1 margin)
                float gw3 = tgw * (1.f / 3.f), gl3 = tgl * (1.f / 3.f);
                int i_lo = max(0, (int)floorf(gxv - gw3) - 1);
                int i_hi = min(NW - 1, (int)floorf(gxv + gw3) + 1);
                int j_lo = max(0, (int)floorf(gyv - gl3) - 1);
                int j_hi = min(NH - 1, (int)floorf(gyv + gl3) + 1);
                int W = i_hi - i_lo + 1, Hh = j_hi - j_lo + 1;
                int total = W * Hh * NA;
                for (int idx = tid; idx < total; idx += 256) {
                    int dx = idx % W;
                    int q2 = idx / W;
                    int j = j_lo + q2 % Hh;
                    int a = q2 / Hh;
                    int i = i_lo + dx;
                    const float* xp = x + (size_t)(b * CH + a * 14) * HW + j * NW + i;
                    float l0 = xp[0], l1 = xp[HW], l2 = xp[2 * HW], l3 = xp[3 * HW];
                    float aw = anchors[2 * a], ah = anchors[2 * a + 1];
                    float bxv = (float)i + 1.f / (1.f + __expf(-l0));
                    float byv = (float)j + 1.f / (1.f + __expf(-l1));
                    float bw = __expf(l2) * aw;
                    float bh = __expf(l3) * ah;
                    float mxv = fminf(bxv - 0.5f * bw, txlo);
                    float Mxv = fmaxf(bxv + 0.5f * bw, txhi);
                    float myv = fminf(byv - 0.5f * bh, tylo);
                    float Myv = fmaxf(byv + 0.5f * bh, tyhi);
                    float cw = bw + tgw - (Mxv - mxv);
                    float chh = bh + tgl - (Myv - myv);
                    // iou > 0.6  <=>  carea > 0.375*(area_b + area_g)
                    if (cw > 0.f && chh > 0.f && cw * chh > 0.375f * bw * bh + tq) {
                        int c = ((b * NA + a) * NH + j) * NW + i;
                        unsigned int old = atomicOr(&mask[c >> 5], 1u << (c & 31));
                        if (!((old >> (c & 31)) & 1u)) {
                            cnt += 1.f;
                            sub += sp_f(xp[6 * HW]);
                        }
                    }
                }
            }
        }
        redA[tid] = sub; redB[tid] = cnt;
        __syncthreads();
        for (int s = 128; s > 0; s >>= 1) {
            if (tid < s) { redA[tid] += redA[tid + s]; redB[tid] += redB[tid + s]; }
            __syncthreads();
        }
        if (tid == 0) { ws[S_SUB + id] = redA[0]; ws[S_CNT + id] = redB[0]; }
    } else if (bx < 2 * NTGT + 1) {
        // ---- winner role: one 8-float private slot each, no atomics -------
        int w = bx - NTGT;                 // 0..NTGT (NTGT == c* slot)
        __shared__ int flag;
        int mt = (w < NTGT) ? meta[w] : 0;
        if (tid == 0) flag = 0;
        __syncthreads();
        if (w == NTGT) {
            for (int id = tid; id < NTGT; id += 256) {
                const float* tp = tgt + (size_t)id * 7;
                float s7 = tp[0] + tp[1] + tp[2] + tp[3] + tp[4] + tp[5] + tp[6];
                if (s7 == 0.f) flag = 1;   // wrap exists (benign monotone race)
            }
        } else if (mt & (1 << 24)) {
            int b = w / NT, t = w - b * NT;
            int key = mt & 0x7FFFF;
            int t2 = t + 1 + tid;
            if (t2 < NT) {
                int m2 = meta[b * NT + t2];
                if ((m2 & (1 << 24)) && ((m2 & 0x7FFFF) == key)) flag = 1;
            }
        }
        __syncthreads();
        if (tid == 0) {
            float slot[8] = {0.f, 0.f, 0.f, 0.f, 0.f, 0.f, 0.f, 0.f};
            if (w == NTGT) {
                // np negative-index wrap cell c*: last invalid row's values
                float sub = 0.f, cnt = 0.f;
                if (flag) {
                    const float* xp = x + (size_t)((NB - 1) * CH + (NA - 1) * 14) * HW
                                      + (HW - 1);
                    float L16 = logf(1e-16f);
                    win_terms(xp, 0.f, 0.f, L16, L16, 0.f, 0.f, 0, slot);
                    int c = NCELL - 1;
                    unsigned int old = atomicOr(&mask[c >> 5], 1u << (c & 31));
                    if (!((old >> (c & 31)) & 1u)) {
                        cnt = 1.f;
                        sub = sp_f(xp[6 * HW]);
                    }
                }
                ws[S_SUB + NTGT] = sub;
                ws[S_CNT + NTGT] = cnt;
            } else if ((mt & (1 << 24)) && !flag) {   // last-t-wins
                int b = w / NT;
                int gi = mt & 255, gj = (mt >> 8) & 255;
                int bn = (mt >> 16) & 7, lab = (mt >> 26) & 7;
                const float* xp = x + (size_t)(b * CH + bn * 14) * HW + gj * NW + gi;
                win_terms(xp, ws[D_GX + w] - (float)gi, ws[D_GY + w] - (float)gj,
                          ws[D_TW + w], ws[D_TL + w],
                          ws[D_TIM + w], ws[D_TRE + w], lab, slot);
            }
            float* dst = ws + S_WIN + w * 8;
            #pragma unroll
            for (int k = 0; k < 8; ++k) dst[k] = slot[k];
        }
    } else {
        // ---- sum role: mask-free grand softplus(l6) total -----------------
        int sx = bx - (2 * NTGT + 1);
        float s = 0.f;
        for (int it = 0; it < SUM_IT; ++it) {
            int c4 = (((it * NSUMB + sx) * 256) + tid) * 4;
            if (c4 < NCELL) {
                int b = c4 / AHW;
                int within = c4 - b * AHW;
                int a = within / HW;
                int rem = within - a * HW;
                const float* p = x + (size_t)(b * CH + a * 14 + 6) * HW + rem;
                float4 v = *(const float4*)p;
                s += sp_f(v.x) + sp_f(v.y) + sp_f(v.z) + sp_f(v.w);
            }
        }
        redA[tid] = s;
        __syncthreads();
        for (int st = 128; st > 0; st >>= 1) {
            if (tid < st) redA[tid] += redA[tid + st];
            __syncthreads();
        }
        if (tid == 0) ws[S_SUM + sx] = redA[0];
    }
}

// ---------------- K3: tiny deterministic reduce + loss assembly ------------
__global__ void __launch_bounds__(256) k_reduce(const float* __restrict__ ws,
                                                float* __restrict__ out) {
    int tid = threadIdx.x;
    double acc[11];
    #pragma unroll
    for (int k = 0; k < 11; ++k) acc[k] = 0.0;
    for (int s = tid; s < NTGT + 1; s += 256) {
        const float* p = ws + S_WIN + s * 8;
        #pragma unroll
        for (int k = 0; k < 8; ++k) acc[k] += (double)p[k];
        acc[8] += (double)ws[S_SUB + s];
        acc[9] += (double)ws[S_CNT + s];
    }
    for (int s = tid; s < NSUMB; s += 256) acc[10] += (double)ws[S_SUM + s];

    __shared__ double R[11][256];
    #pragma unroll
    for (int k = 0; k < 11; ++k) R[k][tid] = acc[k];
    __syncthreads();
    for (int st = 128; st > 0; st >>= 1) {
        if (tid < st) {
            #pragma unroll
            for (int k = 0; k < 11; ++k) R[k][tid] += R[k][tid + st];
        }
        __syncthreads();
    }
    if (tid == 0) {
        double nM  = fmax(R[7][0], 1.0);
        double scf = fmax((double)NCELL - R[9][0], 1.0);
        double bce = R[10][0] - R[8][0];
        double loss =
            (R[0][0] + R[1][0] + R[2][0] + R[3][0] + R[4][0] + R[5][0]) / nM
            + bce / scf
            + (1.0 / NB) * R[6][0] / nM;
        out[0] = (float)loss;
    }
}

extern "C" void kernel_launch(void* const* d_in, const int* in_sizes, int n_in,
                              void* d_out, int out_size, void* d_ws, size_t ws_size,
                              hipStream_t stream) {
    const float* x   = (const float*)d_in[0];
    const float* tgt = (const float*)d_in[1];
    const float* anc = (const float*)d_in[2];
    float* ws  = (float*)d_ws;
    float* out = (float*)d_out;

    hipLaunchKernelGGL(k_prep_zero, dim3((NWORDS + 255) / 256), dim3(256), 0, stream,
                       tgt, anc, ws);
    hipLaunchKernelGGL(k_work, dim3(GRID2), dim3(256), 0, stream, x, tgt, anc, ws);
    hipLaunchKernelGGL(k_reduce, dim3(1), dim3(256), 0, stream, ws, out);
}